// Round 1
// baseline (115.777 us; speedup 1.0000x reference)
//
#include <hip/hip_runtime.h>
#include <math.h>

#define BB 4
#define CC 128
#define KK 32
#define NN 4096
#define NSLICE 32   // n-slices for the numerator GEMM

// ---------------------------------------------------------------------------
// K0: per-(k,c) precompute: w2 = 1/(sigmoid(sp)+1e-7)^2, aw2 = 2*a*w2,
//     ck[k] = sum_c a^2*w2, inv = 1/(sigmoid(sp)+1e-7)
// wtab layout: [channel c][k] as float2(w2, aw2)  -> wave-uniform reads later
// ---------------------------------------------------------------------------
__launch_bounds__(128)
__global__ void k_prep(const float* __restrict__ anchor, const float* __restrict__ sigp,
                       float2* __restrict__ wtab, float* __restrict__ ck,
                       float* __restrict__ inv) {
  const int k = blockIdx.x, c = threadIdx.x;
  float sp = sigp[k * CC + c];
  float s  = 1.0f / (1.0f + expf(-sp));
  float iv = 1.0f / (s + 1e-7f);
  float w2 = iv * iv;
  float a  = anchor[k * CC + c];
  wtab[c * KK + k] = make_float2(w2, 2.0f * a * w2);
  inv[k * CC + c] = iv;
  __shared__ float red[128];
  red[c] = a * a * w2;
  __syncthreads();
  for (int sft = 64; sft > 0; sft >>= 1) {
    if (c < sft) red[c] += red[c + sft];
    __syncthreads();
  }
  if (c == 0) ck[k] = red[0];
}

// ---------------------------------------------------------------------------
// K1: logits + softmax over k -> sa[b][k][n]
// block = 256 thr = 4 waves; wave h handles c in [h*32, h*32+32); 64 n per block
// wtab reads are wave-uniform -> scalar loads (readfirstlane on h)
// ---------------------------------------------------------------------------
__launch_bounds__(256)
__global__ void k_soft(const float* __restrict__ x, const float2* __restrict__ wtab,
                       const float* __restrict__ ck, float* __restrict__ sa) {
  const int b  = blockIdx.y;
  const int n0 = blockIdx.x * 64;
  const int t  = threadIdx.x;
  const int nl = t & 63;
  const int h  = __builtin_amdgcn_readfirstlane(t >> 6);  // wave-uniform 0..3

  __shared__ float red[3][64][33];  // partial logit sums from waves 1..3

  float acc[KK];
#pragma unroll
  for (int k = 0; k < KK; k++) acc[k] = 0.0f;

  const float*  xp = x + ((size_t)b * CC + (size_t)h * 32) * NN + n0 + nl;
  const float2* wp = wtab + (size_t)h * 32 * KK;

#pragma unroll
  for (int c = 0; c < 32; c++) {
    float xv = xp[(size_t)c * NN];
#pragma unroll
    for (int k = 0; k < KK; k++) {
      float2 w = wp[c * KK + k];                      // s_load (uniform addr)
      acc[k] = fmaf(xv, fmaf(xv, w.x, -w.y), acc[k]); // x*(x*w2 - 2*a*w2)
    }
  }

  if (h) {
#pragma unroll
    for (int k = 0; k < KK; k++) red[h - 1][nl][k] = acc[k];
  }
  __syncthreads();
  if (h == 0) {
    float m = -1e30f;
#pragma unroll
    for (int k = 0; k < KK; k++) {
      acc[k] += red[0][nl][k] + red[1][nl][k] + red[2][nl][k];
      acc[k] = -0.5f * (acc[k] + ck[k]);
      m = fmaxf(m, acc[k]);
    }
    float sum = 0.0f;
#pragma unroll
    for (int k = 0; k < KK; k++) { acc[k] = __expf(acc[k] - m); sum += acc[k]; }
    float rs = 1.0f / sum;
    float* spt = sa + (size_t)b * KK * NN + n0 + nl;
#pragma unroll
    for (int k = 0; k < KK; k++) spt[(size_t)k * NN] = acc[k] * rs;
  }
}

// ---------------------------------------------------------------------------
// K2: partial numerator GEMM per n-slice (no atomics -> deterministic):
//   pnum[b][s][k][c] = sum_{n in slice} sa[b][k][n] * x[b][c][n]
//   pden[b][s][k]    = sum_{n in slice} sa[b][k][n]
// block = (slice s, b); 128 n per slice; x staged in LDS in two c-halves
// ---------------------------------------------------------------------------
__launch_bounds__(256)
__global__ void k_num(const float* __restrict__ x, const float* __restrict__ sa,
                      float* __restrict__ pnum, float* __restrict__ pden) {
  const int b = blockIdx.y, s = blockIdx.x;
  const int n0 = s * 128;
  const int t = threadIdx.x;
  __shared__ float xt[64][129];
  __shared__ float st[KK][129];
  const int k = t >> 3, c8 = t & 7;

  for (int i = t; i < KK * 128; i += 256) {
    int kk = i >> 7, j = i & 127;
    st[kk][j] = sa[((size_t)b * KK + kk) * NN + n0 + j];
  }

  float acc[16];
#pragma unroll
  for (int i = 0; i < 16; i++) acc[i] = 0.0f;

  for (int half = 0; half < 2; half++) {
    __syncthreads();
    for (int i = t; i < 64 * 128; i += 256) {
      int cc = i >> 7, j = i & 127;
      xt[cc][j] = x[((size_t)b * CC + half * 64 + cc) * NN + n0 + j];
    }
    __syncthreads();
#pragma unroll 2
    for (int j = 0; j < 128; j++) {
      float sv = st[k][j];
#pragma unroll
      for (int ii = 0; ii < 8; ii++)
        acc[half * 8 + ii] = fmaf(sv, xt[c8 + 8 * ii][j], acc[half * 8 + ii]);
    }
  }

  float* pp = pnum + (((size_t)b * NSLICE + s) * KK + k) * CC;
#pragma unroll
  for (int idx = 0; idx < 16; idx++) pp[c8 + 8 * idx] = acc[idx];  // c = c8+8*idx

  if (c8 == 0) {
    float sum = 0.0f;
    for (int j = 0; j < 128; j++) sum += st[k][j];
    pden[((size_t)b * NSLICE + s) * KK + k] = sum;
  }
}

// ---------------------------------------------------------------------------
// K3: reduce partials, nodes normalize (per-k then global), reshape-view,
//     adj = softmax(G^T G), support = G^T W ... wait: support[k,d]=sum_c G[c,k]W[c,d],
//     graph2 = relu((adj @ support)^T) -> GB[b][c=d][k]
// one block per b
// ---------------------------------------------------------------------------
__launch_bounds__(256)
__global__ void k_gcn(const float* __restrict__ pnum, const float* __restrict__ pden,
                      const float* __restrict__ inv, const float* __restrict__ anchor,
                      const float* __restrict__ W, float* __restrict__ GB) {
  const int b = blockIdx.x;
  const int t = threadIdx.x;
  __shared__ float flat[KK * CC];   // nodes flat[k*128+c]; graph view: flat[i*32+j]
  __shared__ float sup[KK][132];
  __shared__ float adjm[KK][33];
  __shared__ float red[KK][8];
  __shared__ float denl[KK], n1s[KK];
  __shared__ float n2s;

  if (t < KK) {
    float s = 0.0f;
    for (int ss = 0; ss < NSLICE; ss++) s += pden[((size_t)b * NSLICE + ss) * KK + t];
    denl[t] = s;
  }
  __syncthreads();

  const int k = t >> 3, c8 = t & 7;
  const float dk = denl[k];
  const float rden = 1.0f / (dk + 1e-7f);

  float qs[16];
#pragma unroll
  for (int i = 0; i < 16; i++) qs[i] = 0.0f;
  for (int ss = 0; ss < NSLICE; ss++) {
    const float* pp = pnum + ((size_t)b * NSLICE + ss) * (KK * CC) + k * CC + c8;
#pragma unroll
    for (int i = 0; i < 16; i++) qs[i] += pp[8 * i];
  }

  float part = 0.0f;
#pragma unroll
  for (int i = 0; i < 16; i++) {
    int c = c8 + 8 * i, idx = k * CC + c;
    float q = inv[idx] * (qs[i] - anchor[idx] * dk) * rden;
    flat[idx] = q;
    part = fmaf(q, q, part);
  }
  red[k][c8] = part;
  __syncthreads();

  if (t < KK) {
    float s2 = 0.0f;
#pragma unroll
    for (int j = 0; j < 8; j++) s2 += red[t][j];
    float n1 = fmaxf(sqrtf(s2), 1e-12f);
    n1s[t] = n1;
    red[t][0] = s2 / (n1 * n1);   // ||nodes_k||^2 after first normalize
  }
  __syncthreads();
  if (t == 0) {
    float tot = 0.0f;
#pragma unroll
    for (int kk2 = 0; kk2 < KK; kk2++) tot += red[kk2][0];
    n2s = fmaxf(sqrtf(tot), 1e-12f);
  }
  __syncthreads();

  float myscal = 1.0f / (n1s[k] * n2s);
#pragma unroll
  for (int i = 0; i < 16; i++) flat[k * CC + c8 + 8 * i] *= myscal;
  __syncthreads();

  // adj[k][l] = sum_{i<128} flat[i*32+k] * flat[i*32+l]
  const int l4 = (t & 7) * 4;
  float aacc[4] = {0, 0, 0, 0};
  for (int i2 = 0; i2 < CC; i2++) {
    float gk = flat[i2 * KK + k];
#pragma unroll
    for (int ii = 0; ii < 4; ii++) aacc[ii] = fmaf(gk, flat[i2 * KK + l4 + ii], aacc[ii]);
  }
#pragma unroll
  for (int ii = 0; ii < 4; ii++) adjm[k][l4 + ii] = aacc[ii];
  __syncthreads();

  if (t < KK) {  // row softmax over l
    float m = -1e30f;
#pragma unroll
    for (int l = 0; l < KK; l++) m = fmaxf(m, adjm[t][l]);
    float s2 = 0.0f;
#pragma unroll
    for (int l = 0; l < KK; l++) { float e = __expf(adjm[t][l] - m); adjm[t][l] = e; s2 += e; }
    float r = 1.0f / s2;
#pragma unroll
    for (int l = 0; l < KK; l++) adjm[t][l] *= r;
  }
  __syncthreads();

  // support[l][d] = sum_c flat[c*32+l] * W[c*128+d]
  const int d = t & 127, l2 = t >> 7;
  float sacc[16];
#pragma unroll
  for (int j = 0; j < 16; j++) sacc[j] = 0.0f;
  for (int cc = 0; cc < CC; cc++) {
    float wv = W[cc * CC + d];
#pragma unroll
    for (int j = 0; j < 16; j++) sacc[j] = fmaf(flat[cc * KK + l2 + 2 * j], wv, sacc[j]);
  }
#pragma unroll
  for (int j = 0; j < 16; j++) sup[l2 + 2 * j][d] = sacc[j];
  __syncthreads();

  // GB[b][d][kk] = relu( sum_l adjm[kk][l] * sup[l][d] )
#pragma unroll
  for (int j = 0; j < 16; j++) {
    int kk2 = l2 + 2 * j;
    float g = 0.0f;
#pragma unroll
    for (int l = 0; l < KK; l++) g = fmaf(adjm[kk2][l], sup[l][d], g);
    GB[((size_t)b * CC + d) * KK + kk2] = fmaxf(g, 0.0f);
  }
}

// ---------------------------------------------------------------------------
// K4: out[b][c][n] = sum_k GB[b][c][k] * sa[b][k][n]
// GB rows wave-uniform -> scalar loads; sa/out coalesced
// ---------------------------------------------------------------------------
__launch_bounds__(256)
__global__ void k_proj(const float* __restrict__ GB, const float* __restrict__ sa,
                       float* __restrict__ out) {
  const int b  = blockIdx.y;
  const int n0 = blockIdx.x * 64;
  const int t  = threadIdx.x;
  const int nl = t & 63;
  const int cg = __builtin_amdgcn_readfirstlane(t >> 6);

  float sreg[KK];
  const float* spt = sa + (size_t)b * KK * NN + n0 + nl;
#pragma unroll
  for (int k = 0; k < KK; k++) sreg[k] = spt[(size_t)k * NN];

  const float* gp = GB + ((size_t)b * CC + (size_t)cg * 32) * KK;
  float* op = out + ((size_t)b * CC + (size_t)cg * 32) * NN + n0 + nl;
#pragma unroll 2
  for (int ci = 0; ci < 32; ci++) {
    float acc = 0.0f;
#pragma unroll
    for (int k = 0; k < KK; k++) acc = fmaf(gp[ci * KK + k], sreg[k], acc);
    op[(size_t)ci * NN] = acc;
  }
}

// ---------------------------------------------------------------------------
extern "C" void kernel_launch(void* const* d_in, const int* in_sizes, int n_in,
                              void* d_out, int out_size, void* d_ws, size_t ws_size,
                              hipStream_t stream) {
  const float* x      = (const float*)d_in[0];
  const float* anchor = (const float*)d_in[1];
  const float* sigp   = (const float*)d_in[2];
  const float* W      = (const float*)d_in[3];
  float* out = (float*)d_out;

  // workspace layout (floats); total ~4.33 MB
  float* ws   = (float*)d_ws;
  float2* wtab = (float2*)ws;          //  8192 floats
  float* ck   = ws + 8192;             //    32 (+pad)
  float* inv  = ws + 8256;             //  4096
  float* pnum = ws + 12352;            // 524288
  float* pden = ws + 536640;           //  4096
  float* GB   = ws + 540736;           // 16384
  float* sa   = ws + 557120;           // 524288

  k_prep<<<dim3(KK), dim3(CC), 0, stream>>>(anchor, sigp, wtab, ck, inv);
  k_soft<<<dim3(NN / 64, BB), dim3(256), 0, stream>>>(x, wtab, ck, sa);
  k_num<<<dim3(NSLICE, BB), dim3(256), 0, stream>>>(x, sa, pnum, pden);
  k_gcn<<<dim3(BB), dim3(256), 0, stream>>>(pnum, pden, inv, anchor, W, GB);
  k_proj<<<dim3(NN / 64, BB), dim3(256), 0, stream>>>(GB, sa, out);
}

// Round 2
// 98.121 us; speedup vs baseline: 1.1799x; 1.1799x over previous
//
#include <hip/hip_runtime.h>
#include <math.h>

#define BB 4
#define CC 128
#define KK 32
#define NN 4096
#define NSLICE 32   // n-slices for the numerator GEMM

// ---------------------------------------------------------------------------
// K0: per-(k,c) precompute: w2 = 1/(sigmoid(sp)+1e-7)^2, aw2 = 2*a*w2,
//     ck[k] = sum_c a^2*w2, inv = 1/(sigmoid(sp)+1e-7)
// ---------------------------------------------------------------------------
__launch_bounds__(128)
__global__ void k_prep(const float* __restrict__ anchor, const float* __restrict__ sigp,
                       float2* __restrict__ wtab, float* __restrict__ ck,
                       float* __restrict__ inv) {
  const int k = blockIdx.x, c = threadIdx.x;
  float sp = sigp[k * CC + c];
  float s  = 1.0f / (1.0f + expf(-sp));
  float iv = 1.0f / (s + 1e-7f);
  float w2 = iv * iv;
  float a  = anchor[k * CC + c];
  wtab[c * KK + k] = make_float2(w2, 2.0f * a * w2);
  inv[k * CC + c] = iv;
  __shared__ float red[128];
  red[c] = a * a * w2;
  __syncthreads();
  for (int sft = 64; sft > 0; sft >>= 1) {
    if (c < sft) red[c] += red[c + sft];
    __syncthreads();
  }
  if (c == 0) ck[k] = red[0];
}

// ---------------------------------------------------------------------------
// K1: logits + softmax over k -> sa[b][k][n]
// ---------------------------------------------------------------------------
__launch_bounds__(256)
__global__ void k_soft(const float* __restrict__ x, const float2* __restrict__ wtab,
                       const float* __restrict__ ck, float* __restrict__ sa) {
  const int b  = blockIdx.y;
  const int n0 = blockIdx.x * 64;
  const int t  = threadIdx.x;
  const int nl = t & 63;
  const int h  = __builtin_amdgcn_readfirstlane(t >> 6);  // wave-uniform 0..3

  __shared__ float red[3][64][33];

  float acc[KK];
#pragma unroll
  for (int k = 0; k < KK; k++) acc[k] = 0.0f;

  const float*  xp = x + ((size_t)b * CC + (size_t)h * 32) * NN + n0 + nl;
  const float2* wp = wtab + (size_t)h * 32 * KK;

#pragma unroll
  for (int c = 0; c < 32; c++) {
    float xv = xp[(size_t)c * NN];
#pragma unroll
    for (int k = 0; k < KK; k++) {
      float2 w = wp[c * KK + k];                      // s_load (uniform addr)
      acc[k] = fmaf(xv, fmaf(xv, w.x, -w.y), acc[k]);
    }
  }

  if (h) {
#pragma unroll
    for (int k = 0; k < KK; k++) red[h - 1][nl][k] = acc[k];
  }
  __syncthreads();
  if (h == 0) {
    float m = -1e30f;
#pragma unroll
    for (int k = 0; k < KK; k++) {
      acc[k] += red[0][nl][k] + red[1][nl][k] + red[2][nl][k];
      acc[k] = -0.5f * (acc[k] + ck[k]);
      m = fmaxf(m, acc[k]);
    }
    float sum = 0.0f;
#pragma unroll
    for (int k = 0; k < KK; k++) { acc[k] = __expf(acc[k] - m); sum += acc[k]; }
    float rs = 1.0f / sum;
    float* spt = sa + (size_t)b * KK * NN + n0 + nl;
#pragma unroll
    for (int k = 0; k < KK; k++) spt[(size_t)k * NN] = acc[k] * rs;
  }
}

// ---------------------------------------------------------------------------
// K2: partial numerator GEMM per n-slice (deterministic, no atomics)
// ---------------------------------------------------------------------------
__launch_bounds__(256)
__global__ void k_num(const float* __restrict__ x, const float* __restrict__ sa,
                      float* __restrict__ pnum, float* __restrict__ pden) {
  const int b = blockIdx.y, s = blockIdx.x;
  const int n0 = s * 128;
  const int t = threadIdx.x;
  __shared__ float xt[64][129];
  __shared__ float st[KK][129];
  const int k = t >> 3, c8 = t & 7;

  for (int i = t; i < KK * 128; i += 256) {
    int kk = i >> 7, j = i & 127;
    st[kk][j] = sa[((size_t)b * KK + kk) * NN + n0 + j];
  }

  float acc[16];
#pragma unroll
  for (int i = 0; i < 16; i++) acc[i] = 0.0f;

  for (int half = 0; half < 2; half++) {
    __syncthreads();
    for (int i = t; i < 64 * 128; i += 256) {
      int cc = i >> 7, j = i & 127;
      xt[cc][j] = x[((size_t)b * CC + half * 64 + cc) * NN + n0 + j];
    }
    __syncthreads();
#pragma unroll 2
    for (int j = 0; j < 128; j++) {
      float sv = st[k][j];
#pragma unroll
      for (int ii = 0; ii < 8; ii++)
        acc[half * 8 + ii] = fmaf(sv, xt[c8 + 8 * ii][j], acc[half * 8 + ii]);
    }
  }

  float* pp = pnum + (((size_t)b * NSLICE + s) * KK + k) * CC;
#pragma unroll
  for (int idx = 0; idx < 16; idx++) pp[c8 + 8 * idx] = acc[idx];

  if (c8 == 0) {
    float sum = 0.0f;
    for (int j = 0; j < 128; j++) sum += st[k][j];
    pden[((size_t)b * NSLICE + s) * KK + k] = sum;
  }
}

// ---------------------------------------------------------------------------
// K2.5 (NEW): reduce pnum/pden over slices at full occupancy; compute
// unnormalized nodes and per-node sum-of-squares.
// grid = 64 blocks x 256; one thread per (b,k,c)
// ---------------------------------------------------------------------------
__launch_bounds__(256)
__global__ void k_red(const float* __restrict__ pnum, const float* __restrict__ pden,
                      const float* __restrict__ inv, const float* __restrict__ anchor,
                      float* __restrict__ nodes, float* __restrict__ n1sq) {
  const int t = threadIdx.x;
  const int g = blockIdx.x * 256 + t;
  const int c = g & 127, k = (g >> 7) & 31, b = g >> 12;

  float dk = 0.0f;
#pragma unroll 8
  for (int s = 0; s < NSLICE; s++) dk += pden[((size_t)b * NSLICE + s) * KK + k];

  float q = 0.0f;
#pragma unroll 8
  for (int s = 0; s < NSLICE; s++)
    q += pnum[(((size_t)b * NSLICE + s) * KK + k) * CC + c];

  const int idx = k * CC + c;
  float val = inv[idx] * (q - anchor[idx] * dk) / (dk + 1e-7f);
  nodes[((size_t)b * KK + k) * CC + c] = val;

  __shared__ float red[256];
  red[t] = val * val;
  __syncthreads();
  for (int sft = 64; sft > 0; sft >>= 1) {
    if ((t & 127) < sft) red[t] += red[t + sft];
    __syncthreads();
  }
  if ((t & 127) == 0) n1sq[b * KK + k] = red[t];
}

// ---------------------------------------------------------------------------
// K3a: normalize (per-node then global), write flatN; adj = softmax(G^T G).
// one block per b (tiny working set: 16 KB)
// ---------------------------------------------------------------------------
__launch_bounds__(256)
__global__ void k_gcn_a(const float* __restrict__ nodes, const float* __restrict__ n1sq,
                        float* __restrict__ flatN, float* __restrict__ adjG) {
  const int b = blockIdx.x;
  const int t = threadIdx.x;
  __shared__ float flat[KK * CC];   // flat[k*128+c]; graph view flat[i*32+j]
  __shared__ float adjm[KK][33];
  __shared__ float sq[KK], n1v[KK];
  __shared__ float n2s;

  if (t < KK) {
    float s2 = n1sq[b * KK + t];
    sq[t] = s2;
    n1v[t] = fmaxf(sqrtf(s2), 1e-12f);
  }
  __syncthreads();
  if (t == 0) {
    float tot = 0.0f;
#pragma unroll
    for (int k = 0; k < KK; k++) tot += sq[k] / (n1v[k] * n1v[k]);
    n2s = fmaxf(sqrtf(tot), 1e-12f);
  }
  __syncthreads();

  const int k = t >> 3, c8 = t & 7;
  const float myscal = 1.0f / (n1v[k] * n2s);
#pragma unroll
  for (int i = 0; i < 16; i++) {
    int idx = k * CC + c8 + 8 * i;
    float v = nodes[(size_t)b * KK * CC + idx] * myscal;
    flat[idx] = v;
    flatN[(size_t)b * KK * CC + idx] = v;
  }
  __syncthreads();

  // adj[k][l] = sum_{i<128} flat[i*32+k] * flat[i*32+l]
  const int l4 = (t & 7) * 4;
  float aacc[4] = {0, 0, 0, 0};
  for (int i2 = 0; i2 < CC; i2++) {
    float gk = flat[i2 * KK + k];
#pragma unroll
    for (int ii = 0; ii < 4; ii++) aacc[ii] = fmaf(gk, flat[i2 * KK + l4 + ii], aacc[ii]);
  }
#pragma unroll
  for (int ii = 0; ii < 4; ii++) adjm[k][l4 + ii] = aacc[ii];
  __syncthreads();

  if (t < KK) {  // row softmax over l
    float m = -1e30f;
#pragma unroll
    for (int l = 0; l < KK; l++) m = fmaxf(m, adjm[t][l]);
    float s2 = 0.0f;
#pragma unroll
    for (int l = 0; l < KK; l++) { float e = __expf(adjm[t][l] - m); adjm[t][l] = e; s2 += e; }
    float r = 1.0f / s2;
#pragma unroll
    for (int l = 0; l < KK; l++) adjG[((size_t)b * KK + t) * KK + l] = adjm[t][l] * r;
  }
}

// ---------------------------------------------------------------------------
// K3b: support[l][d] = sum_c flat[c*32+l]*W[c*128+d]; GB = relu(adj@sup)^T
// grid = (4 d-chunks, B); block 256
// ---------------------------------------------------------------------------
__launch_bounds__(256)
__global__ void k_gcn_b(const float* __restrict__ flatN, const float* __restrict__ adjG,
                        const float* __restrict__ W, float* __restrict__ GB) {
  const int b = blockIdx.y, dc = blockIdx.x;
  const int t = threadIdx.x;
  const int dl = t & 31, d = dc * 32 + dl;
  const int lq = t >> 5;  // 0..7

  __shared__ float flat[KK * CC];
  __shared__ float sup[KK][33];
  __shared__ float adjs[KK][KK];

  for (int i = t; i < KK * CC; i += 256) flat[i] = flatN[(size_t)b * KK * CC + i];
  for (int i = t; i < KK * KK; i += 256) adjs[i >> 5][i & 31] = adjG[(size_t)b * KK * KK + i];
  __syncthreads();

  float acc[4] = {0, 0, 0, 0};
  for (int c = 0; c < CC; c++) {
    float wv = W[c * CC + d];
#pragma unroll
    for (int j = 0; j < 4; j++) acc[j] = fmaf(flat[c * KK + lq + 8 * j], wv, acc[j]);
  }
#pragma unroll
  for (int j = 0; j < 4; j++) sup[lq + 8 * j][dl] = acc[j];
  __syncthreads();

#pragma unroll
  for (int j = 0; j < 4; j++) {
    int kk = lq + 8 * j;
    float g = 0.0f;
#pragma unroll
    for (int l = 0; l < KK; l++) g = fmaf(adjs[kk][l], sup[l][dl], g);
    GB[((size_t)b * CC + d) * KK + kk] = fmaxf(g, 0.0f);
  }
}

// ---------------------------------------------------------------------------
// K4: out[b][c][n] = sum_k GB[b][c][k] * sa[b][k][n]
// ---------------------------------------------------------------------------
__launch_bounds__(256)
__global__ void k_proj(const float* __restrict__ GB, const float* __restrict__ sa,
                       float* __restrict__ out) {
  const int b  = blockIdx.y;
  const int n0 = blockIdx.x * 64;
  const int t  = threadIdx.x;
  const int nl = t & 63;
  const int cg = __builtin_amdgcn_readfirstlane(t >> 6);

  float sreg[KK];
  const float* spt = sa + (size_t)b * KK * NN + n0 + nl;
#pragma unroll
  for (int k = 0; k < KK; k++) sreg[k] = spt[(size_t)k * NN];

  const float* gp = GB + ((size_t)b * CC + (size_t)cg * 32) * KK;
  float* op = out + ((size_t)b * CC + (size_t)cg * 32) * NN + n0 + nl;
#pragma unroll 2
  for (int ci = 0; ci < 32; ci++) {
    float acc = 0.0f;
#pragma unroll
    for (int k = 0; k < KK; k++) acc = fmaf(gp[ci * KK + k], sreg[k], acc);
    op[(size_t)ci * NN] = acc;
  }
}

// ---------------------------------------------------------------------------
extern "C" void kernel_launch(void* const* d_in, const int* in_sizes, int n_in,
                              void* d_out, int out_size, void* d_ws, size_t ws_size,
                              hipStream_t stream) {
  const float* x      = (const float*)d_in[0];
  const float* anchor = (const float*)d_in[1];
  const float* sigp   = (const float*)d_in[2];
  const float* W      = (const float*)d_in[3];
  float* out = (float*)d_out;

  // workspace layout (floats); total ~4.47 MB
  float* ws    = (float*)d_ws;
  float2* wtab = (float2*)ws;          //  8192 floats
  float* ck    = ws + 8192;            //    64 (32 + pad)
  float* inv   = ws + 8256;            //  4096
  float* pnum  = ws + 12352;           // 524288
  float* pden  = ws + 536640;          //  4096
  float* GB    = ws + 540736;          // 16384
  float* sa    = ws + 557120;          // 524288
  float* nodes = ws + 1081408;         // 16384
  float* n1sq  = ws + 1097792;         //   128
  float* flatN = ws + 1097920;         // 16384
  float* adjG  = ws + 1114304;         //  4096

  k_prep<<<dim3(KK), dim3(CC), 0, stream>>>(anchor, sigp, wtab, ck, inv);
  k_soft<<<dim3(NN / 64, BB), dim3(256), 0, stream>>>(x, wtab, ck, sa);
  k_num<<<dim3(NSLICE, BB), dim3(256), 0, stream>>>(x, sa, pnum, pden);
  k_red<<<dim3(BB * KK * CC / 256), dim3(256), 0, stream>>>(pnum, pden, inv, anchor, nodes, n1sq);
  k_gcn_a<<<dim3(BB), dim3(256), 0, stream>>>(nodes, n1sq, flatN, adjG);
  k_gcn_b<<<dim3(4, BB), dim3(256), 0, stream>>>(flatN, adjG, W, GB);
  k_proj<<<dim3(NN / 64, BB), dim3(256), 0, stream>>>(GB, sa, out);
}

// Round 3
// 91.670 us; speedup vs baseline: 1.2630x; 1.0704x over previous
//
#include <hip/hip_runtime.h>
#include <math.h>

#define BB 4
#define CC 128
#define KK 32
#define NN 4096
#define NSL 64   // 64-pixel slices: NN/64

// ---------------------------------------------------------------------------
// K0: per-(k,c) precompute: w2 = 1/(sigmoid(sp)+1e-7)^2, aw2 = 2*a*w2,
//     ck[k] = sum_c a^2*w2, inv = 1/(sigmoid(sp)+1e-7)
// ---------------------------------------------------------------------------
__launch_bounds__(128)
__global__ void k_prep(const float* __restrict__ anchor, const float* __restrict__ sigp,
                       float2* __restrict__ wtab, float* __restrict__ ck,
                       float* __restrict__ inv) {
  const int k = blockIdx.x, c = threadIdx.x;
  float sp = sigp[k * CC + c];
  float s  = 1.0f / (1.0f + expf(-sp));
  float iv = 1.0f / (s + 1e-7f);
  float w2 = iv * iv;
  float a  = anchor[k * CC + c];
  wtab[c * KK + k] = make_float2(w2, 2.0f * a * w2);
  inv[k * CC + c] = iv;
  __shared__ float red[128];
  red[c] = a * a * w2;
  __syncthreads();
  for (int sft = 64; sft > 0; sft >>= 1) {
    if (c < sft) red[c] += red[c + sft];
    __syncthreads();
  }
  if (c == 0) ck[k] = red[0];
}

// ---------------------------------------------------------------------------
// K1 (fused soft+num): per (b, 64-pixel slice):
//   logits -> softmax over k -> sa (global + LDS), x tile parked in LDS,
//   then partial numerator GEMM pnum[b][s][k][c], pden[b][s][k].
// ---------------------------------------------------------------------------
__launch_bounds__(256)
__global__ void k_fused(const float* __restrict__ x, const float2* __restrict__ wtab,
                        const float* __restrict__ ck, float* __restrict__ sa,
                        float* __restrict__ pnum, float* __restrict__ pden) {
  const int b  = blockIdx.y;
  const int s  = blockIdx.x;
  const int n0 = s * 64;
  const int t  = threadIdx.x;
  const int nl = t & 63;
  const int h  = __builtin_amdgcn_readfirstlane(t >> 6);  // wave-uniform 0..3

  __shared__ float xt[CC][66];       // x tile [c][n]
  __shared__ float st[KK][66];       // soft-assign tile [k][n]
  __shared__ float red[3][64][33];   // logit partials from waves 1..3

  float acc[KK];
#pragma unroll
  for (int k = 0; k < KK; k++) acc[k] = 0.0f;

  const float*  xp = x + ((size_t)b * CC + (size_t)h * 32) * NN + n0 + nl;
  const float2* wp = wtab + (size_t)h * 32 * KK;

#pragma unroll
  for (int c = 0; c < 32; c++) {
    float xv = xp[(size_t)c * NN];
    xt[h * 32 + c][nl] = xv;
#pragma unroll
    for (int k = 0; k < KK; k++) {
      float2 w = wp[c * KK + k];                      // s_load (uniform addr)
      acc[k] = fmaf(xv, fmaf(xv, w.x, -w.y), acc[k]); // x*(x*w2 - 2*a*w2)
    }
  }

  if (h) {
#pragma unroll
    for (int k = 0; k < KK; k++) red[h - 1][nl][k] = acc[k];
  }
  __syncthreads();
  if (h == 0) {
    float m = -1e30f;
#pragma unroll
    for (int k = 0; k < KK; k++) {
      acc[k] += red[0][nl][k] + red[1][nl][k] + red[2][nl][k];
      acc[k] = -0.5f * (acc[k] + ck[k]);
      m = fmaxf(m, acc[k]);
    }
    float sum = 0.0f;
#pragma unroll
    for (int k = 0; k < KK; k++) { acc[k] = __expf(acc[k] - m); sum += acc[k]; }
    float rs = 1.0f / sum;
    float* spt = sa + (size_t)b * KK * NN + n0 + nl;
#pragma unroll
    for (int k = 0; k < KK; k++) {
      float v = acc[k] * rs;
      st[k][nl] = v;
      spt[(size_t)k * NN] = v;
    }
  }
  __syncthreads();

  if (t < KK) {
    float sum = 0.0f;
#pragma unroll
    for (int j = 0; j < 64; j++) sum += st[t][j];
    pden[((size_t)b * NSL + s) * KK + t] = sum;
  }

  const int k = t >> 3, c8 = t & 7;
  float a2[16];
#pragma unroll
  for (int i = 0; i < 16; i++) a2[i] = 0.0f;
#pragma unroll 4
  for (int j = 0; j < 64; j++) {
    float sv = st[k][j];
#pragma unroll
    for (int ii = 0; ii < 16; ii++)
      a2[ii] = fmaf(sv, xt[c8 + 8 * ii][j], a2[ii]);
  }
  float* pp = pnum + (((size_t)b * NSL + s) * KK + k) * CC;
#pragma unroll
  for (int ii = 0; ii < 16; ii++) pp[c8 + 8 * ii] = a2[ii];
}

// ---------------------------------------------------------------------------
// K2 (full GCN, 1024 threads, 1 block per b):
//   reduce pnum/pden over 64 slices (float4, coalesced), nodes + both
//   normalizations, adj = softmax(G^T G), support = G^T W,
//   GB = relu(adj @ support)^T
// ---------------------------------------------------------------------------
__launch_bounds__(1024)
__global__ void k_gcn(const float* __restrict__ pnum, const float* __restrict__ pden,
                      const float* __restrict__ inv, const float* __restrict__ anchor,
                      const float* __restrict__ W, float* __restrict__ GB) {
  const int b = blockIdx.x;
  const int t = threadIdx.x;
  __shared__ float flat[KK * CC];    // nodes flat[k*128+c]; graph view flat[i*32+j]
  __shared__ float sup[KK][130];
  __shared__ float adjm[KK][33];
  __shared__ float redp[32][33];
  __shared__ float denl[KK], n1v[KK], nsq[KK];
  __shared__ float n2s;

  {  // pden reduce: 1024 threads -> 32 partials per k
    int kk = t & 31, sg = t >> 5;
    float p = pden[((size_t)b * NSL + sg) * KK + kk]
            + pden[((size_t)b * NSL + 32 + sg) * KK + kk];
    redp[sg][kk] = p;
  }
  __syncthreads();
  if (t < KK) {
    float d = 0.0f;
#pragma unroll
    for (int sg = 0; sg < 32; sg++) d += redp[sg][t];
    denl[t] = d;
  }
  __syncthreads();

  // pnum reduce: thread (k, cq) owns float4 of channels 4cq..4cq+3
  const int k = t >> 5, cq = t & 31;
  const float4* p4 = (const float4*)pnum;
  float4 q = make_float4(0.0f, 0.0f, 0.0f, 0.0f);
#pragma unroll 8
  for (int s = 0; s < NSL; s++) {
    float4 v = p4[((size_t)b * NSL + s) * (KK * CC / 4) + k * 32 + cq];
    q.x += v.x; q.y += v.y; q.z += v.z; q.w += v.w;
  }
  const float dk = denl[k];
  const float rden = 1.0f / (dk + 1e-7f);
  const int idx4 = k * 32 + cq;
  float4 iv = ((const float4*)inv)[idx4];
  float4 av = ((const float4*)anchor)[idx4];
  float4 val;
  val.x = iv.x * (q.x - av.x * dk) * rden;
  val.y = iv.y * (q.y - av.y * dk) * rden;
  val.z = iv.z * (q.z - av.z * dk) * rden;
  val.w = iv.w * (q.w - av.w * dk) * rden;
  redp[cq][k] = val.x * val.x + val.y * val.y + val.z * val.z + val.w * val.w;
  __syncthreads();
  if (t < KK) {
    float s2 = 0.0f;
#pragma unroll
    for (int j = 0; j < 32; j++) s2 += redp[j][t];
    float n1 = fmaxf(sqrtf(s2), 1e-12f);
    n1v[t] = n1;
    nsq[t] = s2 / (n1 * n1);
  }
  __syncthreads();
  if (t == 0) {
    float tot = 0.0f;
#pragma unroll
    for (int kk = 0; kk < KK; kk++) tot += nsq[kk];
    n2s = fmaxf(sqrtf(tot), 1e-12f);
  }
  __syncthreads();
  {
    float sc = 1.0f / (n1v[k] * n2s);
    val.x *= sc; val.y *= sc; val.z *= sc; val.w *= sc;
    ((float4*)flat)[idx4] = val;
  }
  __syncthreads();

  {  // adj[k2][l] = sum_i flat[i*32+k2]*flat[i*32+l]
    const int k2 = t >> 5, l = t & 31;
    float a = 0.0f;
#pragma unroll 8
    for (int i = 0; i < CC; i++)
      a = fmaf(flat[i * KK + k2], flat[i * KK + l], a);
    adjm[k2][l] = a;
  }
  __syncthreads();
  if (t < KK) {  // row softmax
    float m = -1e30f;
#pragma unroll
    for (int l = 0; l < KK; l++) m = fmaxf(m, adjm[t][l]);
    float s2 = 0.0f;
#pragma unroll
    for (int l = 0; l < KK; l++) { float e = __expf(adjm[t][l] - m); adjm[t][l] = e; s2 += e; }
    float r = 1.0f / s2;
#pragma unroll
    for (int l = 0; l < KK; l++) adjm[t][l] *= r;
  }
  __syncthreads();

  // support[l][d] = sum_c flat[c*32+l] * W[c*128+d]
  const int d = t & 127, lg = t >> 7;  // lg 0..7
  float sacc[4] = {0.0f, 0.0f, 0.0f, 0.0f};
  for (int c = 0; c < CC; c++) {
    float wv = W[c * CC + d];
#pragma unroll
    for (int j = 0; j < 4; j++)
      sacc[j] = fmaf(flat[c * KK + lg + 8 * j], wv, sacc[j]);
  }
#pragma unroll
  for (int j = 0; j < 4; j++) sup[lg + 8 * j][d] = sacc[j];
  __syncthreads();

#pragma unroll
  for (int j = 0; j < 4; j++) {
    int kk = lg + 8 * j;
    float g = 0.0f;
#pragma unroll
    for (int l = 0; l < KK; l++) g = fmaf(adjm[kk][l], sup[l][d], g);
    GB[((size_t)b * CC + d) * KK + kk] = fmaxf(g, 0.0f);
  }
}

// ---------------------------------------------------------------------------
// K3: out[b][c][n] = sum_k GB[b][c][k] * sa[b][k][n]
// ---------------------------------------------------------------------------
__launch_bounds__(256)
__global__ void k_proj(const float* __restrict__ GB, const float* __restrict__ sa,
                       float* __restrict__ out) {
  const int b  = blockIdx.y;
  const int n0 = blockIdx.x * 64;
  const int t  = threadIdx.x;
  const int nl = t & 63;
  const int cg = __builtin_amdgcn_readfirstlane(t >> 6);

  float sreg[KK];
  const float* spt = sa + (size_t)b * KK * NN + n0 + nl;
#pragma unroll
  for (int k = 0; k < KK; k++) sreg[k] = spt[(size_t)k * NN];

  const float* gp = GB + ((size_t)b * CC + (size_t)cg * 32) * KK;
  float* op = out + ((size_t)b * CC + (size_t)cg * 32) * NN + n0 + nl;
#pragma unroll 2
  for (int ci = 0; ci < 32; ci++) {
    float acc = 0.0f;
#pragma unroll
    for (int k = 0; k < KK; k++) acc = fmaf(gp[ci * KK + k], sreg[k], acc);
    op[(size_t)ci * NN] = acc;
  }
}

// ---------------------------------------------------------------------------
extern "C" void kernel_launch(void* const* d_in, const int* in_sizes, int n_in,
                              void* d_out, int out_size, void* d_ws, size_t ws_size,
                              hipStream_t stream) {
  const float* x      = (const float*)d_in[0];
  const float* anchor = (const float*)d_in[1];
  const float* sigp   = (const float*)d_in[2];
  const float* W      = (const float*)d_in[3];
  float* out = (float*)d_out;

  // workspace layout (floats); total ~6.5 MB; all float4-aligned
  float* ws    = (float*)d_ws;
  float2* wtab = (float2*)ws;          //    8192 floats
  float* ck    = ws + 8192;            //      64 (32 + pad)
  float* inv   = ws + 8256;            //    4096
  float* pnum  = ws + 12352;           // 1048576 (4*64*32*128)
  float* pden  = ws + 1060928;         //    8192
  float* GB    = ws + 1069120;         //   16384
  float* sa    = ws + 1085504;         //  524288

  k_prep <<<dim3(KK),        dim3(CC),   0, stream>>>(anchor, sigp, wtab, ck, inv);
  k_fused<<<dim3(NSL, BB),   dim3(256),  0, stream>>>(x, wtab, ck, sa, pnum, pden);
  k_gcn  <<<dim3(BB),        dim3(1024), 0, stream>>>(pnum, pden, inv, anchor, W, GB);
  k_proj <<<dim3(NN / 64, BB), dim3(256), 0, stream>>>(GB, sa, out);
}